// Round 10
// baseline (237.630 us; speedup 1.0000x reference)
//
#include <hip/hip_runtime.h>

#define NB 8
#define TT 8192
#define NN 256
#define BT (NB*TT)        // 65536 rows total
#define CH 64             // chunk length (== GEMM M-tile)
#define NCHUNK (BT/CH)    // 1024
#define GPB (TT/CH)       // 128 chunks per sequence

typedef float f4 __attribute__((ext_vector_type(4)));
typedef unsigned u4 __attribute__((ext_vector_type(4)));
typedef short b8 __attribute__((ext_vector_type(8)));

static __device__ __forceinline__ ushort f2bf(float f) {
  union { float f; unsigned u; } v; v.f = f;
  return (ushort)((v.u + 0x7fffu + ((v.u >> 16) & 1u)) >> 16);  // RNE
}
static __device__ __forceinline__ float bf2f(ushort h) {
  union { unsigned u; float f; } v; v.u = ((unsigned)h) << 16; return v.f;
}

// ---------------- setup: params + bf16 weight copies + Lpow table (VERBATIM R9) ----
__global__ void k_setup(const float* __restrict__ nu_log, const float* __restrict__ theta_log,
                        const float* __restrict__ gamma_log,
                        const float* __restrict__ B_re, const float* __restrict__ B_im,
                        const float* __restrict__ C_re, const float* __restrict__ C_im,
                        float2* __restrict__ Lc, float2* __restrict__ LCH,
                        float2* __restrict__ Lpow,
                        ushort* __restrict__ BnRe, ushort* __restrict__ BnIm,
                        ushort* __restrict__ CRe, ushort* __restrict__ CIm) {
  int bid = blockIdx.x, tid = threadIdx.x;
  if (bid < NN) {
    int m = bid, n = tid;
    float g = expf(gamma_log[m]);
    int idx = m * NN + n;
    BnRe[idx] = f2bf(B_re[idx] * g);
    BnIm[idx] = f2bf(B_im[idx] * g);
    CRe[idx]  = f2bf(C_re[idx]);
    CIm[idx]  = f2bf(-C_im[idx]);   // pre-negated so GEMM2 is pure accumulate
  } else {
    int m = tid;
    float Lmod = expf(-expf(nu_log[m]));
    float th = expf(theta_log[m]);
    float lre = Lmod * cosf(th), lim = Lmod * sinf(th);
    Lc[m] = make_float2(lre, lim);
    float pr = 1.f, pi = 0.f;
    for (int k = 0; k < CH; ++k) {
      // Lpow[t][m] = L^(CH-1-t): weight of Bu[t] in the chunk carry
      Lpow[(size_t)(CH - 1 - k) * NN + m] = make_float2(pr, pi);  // L^k
      float npr = pr * lre - pi * lim;
      pi = pr * lim + pi * lre;
      pr = npr;
    }
    LCH[m] = make_float2(pr, pi);   // L^CH
  }
}

// ---------------- K1: GEMM1 in regs -> weighted reduce -> carry (VERBATIM R9) ----
__global__ __launch_bounds__(256) void k_carry(const float* __restrict__ x,
                                               const ushort* __restrict__ BnRe,
                                               const ushort* __restrict__ BnIm,
                                               const float2* __restrict__ Lpow,
                                               float2* __restrict__ carry) {
  int cid = blockIdx.x, tid = threadIdx.x;
  int lane = tid & 63, wid = tid >> 6;
  int lr = lane & 15, lg = lane >> 4;
  int mq = wid * 64;
  int tbase = cid * CH;

  f4 accRe[4][4], accIm[4][4];
  for (int i = 0; i < 4; ++i)
    for (int j = 0; j < 4; ++j) { accRe[i][j] = (f4)0.f; accIm[i][j] = (f4)0.f; }

  for (int ks = 0; ks < 8; ++ks) {
    int k0 = ks * 32 + lg * 8;
    b8 a[4];
    for (int mf = 0; mf < 4; ++mf) {
      const float* px = x + (size_t)(tbase + mf * 16 + lr) * NN + k0;
      f4 x0 = *(const f4*)px;
      f4 x1 = *(const f4*)(px + 4);
      b8 t;
      t[0] = (short)f2bf(x0[0]); t[1] = (short)f2bf(x0[1]);
      t[2] = (short)f2bf(x0[2]); t[3] = (short)f2bf(x0[3]);
      t[4] = (short)f2bf(x1[0]); t[5] = (short)f2bf(x1[1]);
      t[6] = (short)f2bf(x1[2]); t[7] = (short)f2bf(x1[3]);
      a[mf] = t;
    }
    for (int nf = 0; nf < 4; ++nf) {
      int mrow = mq + nf * 16 + lr;
      b8 br = *(const b8*)(BnRe + (size_t)mrow * NN + k0);
      b8 bi = *(const b8*)(BnIm + (size_t)mrow * NN + k0);
      for (int mf = 0; mf < 4; ++mf) {
        accRe[mf][nf] = __builtin_amdgcn_mfma_f32_16x16x32_bf16(a[mf], br, accRe[mf][nf], 0, 0, 0);
        accIm[mf][nf] = __builtin_amdgcn_mfma_f32_16x16x32_bf16(a[mf], bi, accIm[mf][nf], 0, 0, 0);
      }
    }
  }

  for (int nf = 0; nf < 4; ++nf) {
    int col = mq + nf * 16 + lr;
    float sr = 0.f, si = 0.f;
    for (int mf = 0; mf < 4; ++mf)
      for (int q = 0; q < 4; ++q) {
        int t = mf * 16 + lg * 4 + q;
        float2 w = Lpow[(size_t)t * NN + col];
        float br = accRe[mf][nf][q], bi = accIm[mf][nf][q];
        sr += w.x * br - w.y * bi;
        si += w.x * bi + w.y * br;
      }
    sr += __shfl_xor(sr, 16, 64);  si += __shfl_xor(si, 16, 64);
    sr += __shfl_xor(sr, 32, 64);  si += __shfl_xor(si, 32, 64);
    if (lg == 0) carry[(size_t)cid * NN + col] = make_float2(sr, si);
  }
}

// ---------------- K2: scan carries across chunks, in place, load-pipelined ----
__global__ void k_seed(float2* __restrict__ carrySeed, const float2* __restrict__ LCH) {
  int b = blockIdx.x, m = threadIdx.x;
  float2 LC = LCH[m];
  float hr = 0.f, hi = 0.f;
  size_t base = (size_t)b * GPB * NN + m;
  float2 c = carrySeed[base];
  for (int g = 0; g < GPB; ++g) {
    size_t idx = base + (size_t)g * NN;
    float2 cn = (g + 1 < GPB) ? carrySeed[idx + NN] : make_float2(0.f, 0.f);
    carrySeed[idx] = make_float2(hr, hi);     // exclusive prefix -> seed
    float nr = LC.x * hr - LC.y * hi + c.x;
    hi = LC.x * hi + LC.y * hr + c.y;
    hr = nr;
    c = cn;
  }
}

// ---------------- K3 (512 thr, 8 waves): GEMM1 -> packed LDS -> scan -> GEMM2 ----
// Packed-u32 LDS layout, swizzles, scan and GEMM2 math identical to R3/R9.
// Each wave owns a 64-row x 32-col slice (col base = wid*32).
__global__ __launch_bounds__(512) void k_out(const float* __restrict__ x,
                                             const ushort* __restrict__ BnRe,
                                             const ushort* __restrict__ BnIm,
                                             const float2* __restrict__ Lc,
                                             const float2* __restrict__ seed,
                                             const ushort* __restrict__ CRe,
                                             const ushort* __restrict__ CIm,
                                             float* __restrict__ out) {
  __shared__ char lds[CH * 1024];
  int cid = blockIdx.x, tid = threadIdx.x;
  size_t rowbase = (size_t)cid * CH;
  int lane = tid & 63, wid = tid >> 6;          // wid 0..7
  int lr = lane & 15, lg = lane >> 4;
  int mq = wid * 32;                             // 32-col slice per wave
  int tbase = cid * CH;

  { // GEMM1: acc[4 mf][2 nf] complex, then packed store to swizzled LDS
    f4 accRe[4][2], accIm[4][2];
    for (int i = 0; i < 4; ++i)
      for (int j = 0; j < 2; ++j) { accRe[i][j] = (f4)0.f; accIm[i][j] = (f4)0.f; }

    for (int ks = 0; ks < 8; ++ks) {
      int k0 = ks * 32 + lg * 8;
      b8 a[4];
      for (int mf = 0; mf < 4; ++mf) {
        const float* px = x + (size_t)(tbase + mf * 16 + lr) * NN + k0;
        f4 x0 = *(const f4*)px;
        f4 x1 = *(const f4*)(px + 4);
        b8 t;
        t[0] = (short)f2bf(x0[0]); t[1] = (short)f2bf(x0[1]);
        t[2] = (short)f2bf(x0[2]); t[3] = (short)f2bf(x0[3]);
        t[4] = (short)f2bf(x1[0]); t[5] = (short)f2bf(x1[1]);
        t[6] = (short)f2bf(x1[2]); t[7] = (short)f2bf(x1[3]);
        a[mf] = t;
      }
      for (int nf = 0; nf < 2; ++nf) {
        int mrow = mq + nf * 16 + lr;
        b8 br = *(const b8*)(BnRe + (size_t)mrow * NN + k0);
        b8 bi = *(const b8*)(BnIm + (size_t)mrow * NN + k0);
        for (int mf = 0; mf < 4; ++mf) {
          accRe[mf][nf] = __builtin_amdgcn_mfma_f32_16x16x32_bf16(a[mf], br, accRe[mf][nf], 0, 0, 0);
          accIm[mf][nf] = __builtin_amdgcn_mfma_f32_16x16x32_bf16(a[mf], bi, accIm[mf][nf], 0, 0, 0);
        }
      }
    }
    for (int mf = 0; mf < 4; ++mf)
      for (int nf = 0; nf < 2; ++nf)
        for (int r = 0; r < 4; ++r) {
          int row = mf * 16 + lg * 4 + r;
          int col = mq + nf * 16 + lr;
          unsigned p = (unsigned)f2bf(accRe[mf][nf][r]) | ((unsigned)f2bf(accIm[mf][nf][r]) << 16);
          int off = row * 1024 + ((col * 4) ^ ((row & 7) << 4));
          *(unsigned*)(lds + off) = p;
        }
  }
  __syncthreads();

  if (tid < NN) { // seeded scan, in place (packed Bu -> packed h), VERBATIM R3
    int c = tid;
    float2 L = Lc[c];
    float2 s = seed[(size_t)cid * NN + c];
    float hr = s.x, hi = s.y;
    for (int k = 0; k < CH; ++k) {
      int off = k * 1024 + ((c * 4) ^ ((k & 7) << 4));
      unsigned u = *(const unsigned*)(lds + off);
      float ur = bf2f((ushort)(u & 0xffffu)), ui = bf2f((ushort)(u >> 16));
      float nr = L.x * hr - L.y * hi + ur;
      hi = L.x * hi + L.y * hr + ui;
      hr = nr;
      *(unsigned*)(lds + off) = (unsigned)f2bf(hr) | ((unsigned)f2bf(hi) << 16);
    }
  }
  __syncthreads();

  // GEMM2: out[t][m] = hRe·CRe + hIm·(-CIm); acc[4 mf][2 nf]
  f4 acc[4][2];
  for (int i = 0; i < 4; ++i)
    for (int j = 0; j < 2; ++j) acc[i][j] = (f4)0.f;

  for (int ks = 0; ks < 8; ++ks) {
    int k0 = ks * 32 + lg * 8;
    b8 ar[4], ai[4];
    for (int mf = 0; mf < 4; ++mf) {
      int row = mf * 16 + lr;
      int m4 = (row & 7) << 4;
      const char* base = lds + row * 1024;
      u4 p0 = *(const u4*)(base + ((k0 * 4) ^ m4));        // channels k0..k0+3 (packed)
      u4 p1 = *(const u4*)(base + ((k0 * 4 + 16) ^ m4));   // channels k0+4..k0+7
      b8 tr, ti;
      tr[0] = (short)(p0[0] & 0xffffu); ti[0] = (short)(p0[0] >> 16);
      tr[1] = (short)(p0[1] & 0xffffu); ti[1] = (short)(p0[1] >> 16);
      tr[2] = (short)(p0[2] & 0xffffu); ti[2] = (short)(p0[2] >> 16);
      tr[3] = (short)(p0[3] & 0xffffu); ti[3] = (short)(p0[3] >> 16);
      tr[4] = (short)(p1[0] & 0xffffu); ti[4] = (short)(p1[0] >> 16);
      tr[5] = (short)(p1[1] & 0xffffu); ti[5] = (short)(p1[1] >> 16);
      tr[6] = (short)(p1[2] & 0xffffu); ti[6] = (short)(p1[2] >> 16);
      tr[7] = (short)(p1[3] & 0xffffu); ti[7] = (short)(p1[3] >> 16);
      ar[mf] = tr; ai[mf] = ti;
    }
    for (int nf = 0; nf < 2; ++nf) {
      int m = mq + nf * 16 + lr;
      b8 cr = *(const b8*)(CRe + (size_t)m * NN + k0);
      b8 ci = *(const b8*)(CIm + (size_t)m * NN + k0);
      for (int mf = 0; mf < 4; ++mf) {
        acc[mf][nf] = __builtin_amdgcn_mfma_f32_16x16x32_bf16(ar[mf], cr, acc[mf][nf], 0, 0, 0);
        acc[mf][nf] = __builtin_amdgcn_mfma_f32_16x16x32_bf16(ai[mf], ci, acc[mf][nf], 0, 0, 0);
      }
    }
  }
  for (int mf = 0; mf < 4; ++mf)
    for (int nf = 0; nf < 2; ++nf)
      for (int r = 0; r < 4; ++r) {
        size_t t = rowbase + mf * 16 + lg * 4 + r;
        out[t * NN + mq + nf * 16 + lr] = acc[mf][nf][r];
      }
}

extern "C" void kernel_launch(void* const* d_in, const int* in_sizes, int n_in,
                              void* d_out, int out_size, void* d_ws, size_t ws_size,
                              hipStream_t stream) {
  const float* x         = (const float*)d_in[0];
  const float* nu_log    = (const float*)d_in[1];
  const float* theta_log = (const float*)d_in[2];
  const float* gamma_log = (const float*)d_in[3];
  const float* B_re      = (const float*)d_in[4];
  const float* B_im      = (const float*)d_in[5];
  const float* C_re      = (const float*)d_in[6];
  const float* C_im      = (const float*)d_in[7];
  float* out = (float*)d_out;

  // d_ws usage: 2,756,608 bytes — VERBATIM R9 layout (passed).
  char* ws = (char*)d_ws;
  float2*  carrySeed = (float2*)(ws + 0);        // 1024*256*8 = 2,097,152
  float2*  Lc   = (float2*)(ws + 2097152);       // 2,048
  float2*  LCH  = (float2*)(ws + 2099200);       // 2,048
  ushort*  BnRe = (ushort*)(ws + 2101248);       // 131,072
  ushort*  BnIm = (ushort*)(ws + 2232320);       // 131,072
  ushort*  CRe  = (ushort*)(ws + 2363392);       // 131,072
  ushort*  CIm  = (ushort*)(ws + 2494464);       // 131,072  (end 2,625,536)
  float2*  Lpow = (float2*)(ws + 2625536);       // 64*256*8 = 131,072 (end 2,756,608)

  hipLaunchKernelGGL(k_setup, dim3(NN + 1), dim3(NN), 0, stream,
                     nu_log, theta_log, gamma_log, B_re, B_im, C_re, C_im,
                     Lc, LCH, Lpow, BnRe, BnIm, CRe, CIm);
  hipLaunchKernelGGL(k_carry, dim3(NCHUNK), dim3(256), 0, stream,
                     x, BnRe, BnIm, Lpow, carrySeed);
  hipLaunchKernelGGL(k_seed, dim3(NB), dim3(NN), 0, stream, carrySeed, LCH);
  hipLaunchKernelGGL(k_out, dim3(NCHUNK), dim3(512), 0, stream,
                     x, BnRe, BnIm, Lc, carrySeed, CRe, CIm, out);
}

// Round 11
// 179.094 us; speedup vs baseline: 1.3268x; 1.3268x over previous
//
#include <hip/hip_runtime.h>

#define NB 8
#define TT 8192
#define NN 256
#define BT (NB*TT)        // 65536 rows total
#define CH 64             // chunk length (== GEMM M-tile)
#define NCHUNK (BT/CH)    // 1024
#define GPB (TT/CH)       // 128 chunks per sequence

typedef float f4 __attribute__((ext_vector_type(4)));
typedef unsigned u4 __attribute__((ext_vector_type(4)));
typedef short b8 __attribute__((ext_vector_type(8)));

static __device__ __forceinline__ ushort f2bf(float f) {
  union { float f; unsigned u; } v; v.f = f;
  return (ushort)((v.u + 0x7fffu + ((v.u >> 16) & 1u)) >> 16);  // RNE
}
static __device__ __forceinline__ float bf2f(ushort h) {
  union { unsigned u; float f; } v; v.u = ((unsigned)h) << 16; return v.f;
}

// ---------------- setup: params + bf16 weight copies + Lpow table (VERBATIM R9) ----
__global__ void k_setup(const float* __restrict__ nu_log, const float* __restrict__ theta_log,
                        const float* __restrict__ gamma_log,
                        const float* __restrict__ B_re, const float* __restrict__ B_im,
                        const float* __restrict__ C_re, const float* __restrict__ C_im,
                        float2* __restrict__ Lc, float2* __restrict__ LCH,
                        float2* __restrict__ Lpow,
                        ushort* __restrict__ BnRe, ushort* __restrict__ BnIm,
                        ushort* __restrict__ CRe, ushort* __restrict__ CIm) {
  int bid = blockIdx.x, tid = threadIdx.x;
  if (bid < NN) {
    int m = bid, n = tid;
    float g = expf(gamma_log[m]);
    int idx = m * NN + n;
    BnRe[idx] = f2bf(B_re[idx] * g);
    BnIm[idx] = f2bf(B_im[idx] * g);
    CRe[idx]  = f2bf(C_re[idx]);
    CIm[idx]  = f2bf(-C_im[idx]);   // pre-negated so GEMM2 is pure accumulate
  } else {
    int m = tid;
    float Lmod = expf(-expf(nu_log[m]));
    float th = expf(theta_log[m]);
    float lre = Lmod * cosf(th), lim = Lmod * sinf(th);
    Lc[m] = make_float2(lre, lim);
    float pr = 1.f, pi = 0.f;
    for (int k = 0; k < CH; ++k) {
      // Lpow[t][m] = L^(CH-1-t): weight of Bu[t] in the chunk carry
      Lpow[(size_t)(CH - 1 - k) * NN + m] = make_float2(pr, pi);  // L^k
      float npr = pr * lre - pi * lim;
      pi = pr * lim + pi * lre;
      pr = npr;
    }
    LCH[m] = make_float2(pr, pi);   // L^CH
  }
}

// ---- stage 64x256 fp32 x tile into LDS (64 KB), coalesced reads, swizzled 16B writes ----
// swizzle: byte offset within row: (c*4) ^ ((r&7)<<4)  (16B quantum, bijective per row)
static __device__ __forceinline__ void stage_x_f32(const float* __restrict__ xt,
                                                   char* lds, int tid) {
#pragma unroll
  for (int i = 0; i < 16; ++i) {
    int fi = i * 1024 + tid * 4;               // float index in 64x256 tile
    f4 w = *(const f4*)(xt + fi);              // wave reads 1 KB contiguous
    int r = fi >> 8, c = fi & 255;
    int dst = r * 1024 + ((c * 4) ^ ((r & 7) << 4));
    *(f4*)(lds + dst) = w;
  }
}

// ---- GEMM1, A-fragments from the staged fp32 LDS tile (numerics identical to R9) ----
static __device__ __forceinline__ void gemm1_ldsx(const char* lds,
                                                  const ushort* __restrict__ BnRe,
                                                  const ushort* __restrict__ BnIm,
                                                  int tid, f4 accRe[4][4], f4 accIm[4][4]) {
  int lane = tid & 63, wid = tid >> 6;
  int lr = lane & 15, lg = lane >> 4;
  int mq = wid * 64;
  for (int ks = 0; ks < 8; ++ks) {
    int k0 = ks * 32 + lg * 8;
    b8 a[4];
    for (int mf = 0; mf < 4; ++mf) {
      int r = mf * 16 + lr;
      int sw = (r & 7) << 4;
      const char* base = lds + r * 1024;
      f4 x0 = *(const f4*)(base + ((k0 * 4) ^ sw));
      f4 x1 = *(const f4*)(base + ((k0 * 4 + 16) ^ sw));
      b8 t;
      t[0] = (short)f2bf(x0[0]); t[1] = (short)f2bf(x0[1]);
      t[2] = (short)f2bf(x0[2]); t[3] = (short)f2bf(x0[3]);
      t[4] = (short)f2bf(x1[0]); t[5] = (short)f2bf(x1[1]);
      t[6] = (short)f2bf(x1[2]); t[7] = (short)f2bf(x1[3]);
      a[mf] = t;
    }
    for (int nf = 0; nf < 4; ++nf) {
      int mrow = mq + nf * 16 + lr;
      b8 br = *(const b8*)(BnRe + (size_t)mrow * NN + k0);
      b8 bi = *(const b8*)(BnIm + (size_t)mrow * NN + k0);
      for (int mf = 0; mf < 4; ++mf) {
        accRe[mf][nf] = __builtin_amdgcn_mfma_f32_16x16x32_bf16(a[mf], br, accRe[mf][nf], 0, 0, 0);
        accIm[mf][nf] = __builtin_amdgcn_mfma_f32_16x16x32_bf16(a[mf], bi, accIm[mf][nf], 0, 0, 0);
      }
    }
  }
}

// ---------------- K1: stage x -> GEMM1(LDS) -> Lpow reduce -> carry (R9 reduce verbatim) ----
__global__ __launch_bounds__(256) void k_carry(const float* __restrict__ x,
                                               const ushort* __restrict__ BnRe,
                                               const ushort* __restrict__ BnIm,
                                               const float2* __restrict__ Lpow,
                                               float2* __restrict__ carry) {
  __shared__ char lds[65536];
  int cid = blockIdx.x, tid = threadIdx.x;
  int lane = tid & 63, wid = tid >> 6;
  int lr = lane & 15, lg = lane >> 4;
  int mq = wid * 64;

  stage_x_f32(x + (size_t)cid * CH * NN, lds, tid);
  __syncthreads();

  f4 accRe[4][4], accIm[4][4];
  for (int i = 0; i < 4; ++i)
    for (int j = 0; j < 4; ++j) { accRe[i][j] = (f4)0.f; accIm[i][j] = (f4)0.f; }
  gemm1_ldsx(lds, BnRe, BnIm, tid, accRe, accIm);

  for (int nf = 0; nf < 4; ++nf) {
    int col = mq + nf * 16 + lr;
    float sr = 0.f, si = 0.f;
    for (int mf = 0; mf < 4; ++mf)
      for (int q = 0; q < 4; ++q) {
        int t = mf * 16 + lg * 4 + q;
        float2 w = Lpow[(size_t)t * NN + col];
        float br = accRe[mf][nf][q], bi = accIm[mf][nf][q];
        sr += w.x * br - w.y * bi;
        si += w.x * bi + w.y * br;
      }
    sr += __shfl_xor(sr, 16, 64);  si += __shfl_xor(si, 16, 64);
    sr += __shfl_xor(sr, 32, 64);  si += __shfl_xor(si, 32, 64);
    if (lg == 0) carry[(size_t)cid * NN + col] = make_float2(sr, si);
  }
}

// ---------------- K2: scan carries across chunks, in place, load-pipelined (R10 verbatim) ----
__global__ void k_seed(float2* __restrict__ carrySeed, const float2* __restrict__ LCH) {
  int b = blockIdx.x, m = threadIdx.x;
  float2 LC = LCH[m];
  float hr = 0.f, hi = 0.f;
  size_t base = (size_t)b * GPB * NN + m;
  float2 c = carrySeed[base];
  for (int g = 0; g < GPB; ++g) {
    size_t idx = base + (size_t)g * NN;
    float2 cn = (g + 1 < GPB) ? carrySeed[idx + NN] : make_float2(0.f, 0.f);
    carrySeed[idx] = make_float2(hr, hi);     // exclusive prefix -> seed
    float nr = LC.x * hr - LC.y * hi + c.x;
    hi = LC.x * hi + LC.y * hr + c.y;
    hr = nr;
    c = cn;
  }
}

// ---------------- K3: stage x -> GEMM1(LDS) -> packed Bu -> scan -> GEMM2 -> out ----
// Packed-u32 Bu layout, scan, GEMM2: VERBATIM R9. Bu tile overwrites x tile after a sync.
__global__ __launch_bounds__(256) void k_out(const float* __restrict__ x,
                                             const ushort* __restrict__ BnRe,
                                             const ushort* __restrict__ BnIm,
                                             const float2* __restrict__ Lc,
                                             const float2* __restrict__ seed,
                                             const ushort* __restrict__ CRe,
                                             const ushort* __restrict__ CIm,
                                             float* __restrict__ out) {
  __shared__ char lds[65536];
  int cid = blockIdx.x, tid = threadIdx.x;
  size_t rowbase = (size_t)cid * CH;
  int lane = tid & 63, wid = tid >> 6;
  int lr = lane & 15, lg = lane >> 4;
  int mq = wid * 64;

  stage_x_f32(x + rowbase * NN, lds, tid);
  __syncthreads();

  f4 accRe[4][4], accIm[4][4];
  for (int i = 0; i < 4; ++i)
    for (int j = 0; j < 4; ++j) { accRe[i][j] = (f4)0.f; accIm[i][j] = (f4)0.f; }
  gemm1_ldsx(lds, BnRe, BnIm, tid, accRe, accIm);
  __syncthreads();   // all GEMM1 LDS reads done before Bu overwrites the x tile

  for (int mf = 0; mf < 4; ++mf)      // packed Bu store (R9 verbatim formula)
    for (int nf = 0; nf < 4; ++nf)
      for (int r = 0; r < 4; ++r) {
        int row = mf * 16 + lg * 4 + r;
        int col = mq + nf * 16 + lr;
        unsigned p = (unsigned)f2bf(accRe[mf][nf][r]) | ((unsigned)f2bf(accIm[mf][nf][r]) << 16);
        int off = row * 1024 + ((col * 4) ^ ((row & 7) << 4));
        *(unsigned*)(lds + off) = p;
      }
  __syncthreads();

  { // seeded scan, in place (packed Bu -> packed h), VERBATIM R9
    int c = tid;
    float2 L = Lc[c];
    float2 s = seed[(size_t)cid * NN + c];
    float hr = s.x, hi = s.y;
    for (int k = 0; k < CH; ++k) {
      int off = k * 1024 + ((c * 4) ^ ((k & 7) << 4));
      unsigned u = *(const unsigned*)(lds + off);
      float ur = bf2f((ushort)(u & 0xffffu)), ui = bf2f((ushort)(u >> 16));
      float nr = L.x * hr - L.y * hi + ur;
      hi = L.x * hi + L.y * hr + ui;
      hr = nr;
      *(unsigned*)(lds + off) = (unsigned)f2bf(hr) | ((unsigned)f2bf(hi) << 16);
    }
  }
  __syncthreads();

  // GEMM2: out[t][m] = hRe·CRe + hIm·(-CIm)  (VERBATIM R9)
  f4 acc[4][4];
  for (int i = 0; i < 4; ++i)
    for (int j = 0; j < 4; ++j) acc[i][j] = (f4)0.f;

  for (int ks = 0; ks < 8; ++ks) {
    int k0 = ks * 32 + lg * 8;
    b8 ar[4], ai[4];
    for (int mf = 0; mf < 4; ++mf) {
      int row = mf * 16 + lr;
      int m4 = (row & 7) << 4;
      const char* base = lds + row * 1024;
      u4 p0 = *(const u4*)(base + ((k0 * 4) ^ m4));        // channels k0..k0+3 (packed)
      u4 p1 = *(const u4*)(base + ((k0 * 4 + 16) ^ m4));   // channels k0+4..k0+7
      b8 tr, ti;
      tr[0] = (short)(p0[0] & 0xffffu); ti[0] = (short)(p0[0] >> 16);
      tr[1] = (short)(p0[1] & 0xffffu); ti[1] = (short)(p0[1] >> 16);
      tr[2] = (short)(p0[2] & 0xffffu); ti[2] = (short)(p0[2] >> 16);
      tr[3] = (short)(p0[3] & 0xffffu); ti[3] = (short)(p0[3] >> 16);
      tr[4] = (short)(p1[0] & 0xffffu); ti[4] = (short)(p1[0] >> 16);
      tr[5] = (short)(p1[1] & 0xffffu); ti[5] = (short)(p1[1] >> 16);
      tr[6] = (short)(p1[2] & 0xffffu); ti[6] = (short)(p1[2] >> 16);
      tr[7] = (short)(p1[3] & 0xffffu); ti[7] = (short)(p1[3] >> 16);
      ar[mf] = tr; ai[mf] = ti;
    }
    for (int nf = 0; nf < 4; ++nf) {
      int m = mq + nf * 16 + lr;
      b8 cr = *(const b8*)(CRe + (size_t)m * NN + k0);
      b8 ci = *(const b8*)(CIm + (size_t)m * NN + k0);
      for (int mf = 0; mf < 4; ++mf) {
        acc[mf][nf] = __builtin_amdgcn_mfma_f32_16x16x32_bf16(ar[mf], cr, acc[mf][nf], 0, 0, 0);
        acc[mf][nf] = __builtin_amdgcn_mfma_f32_16x16x32_bf16(ai[mf], ci, acc[mf][nf], 0, 0, 0);
      }
    }
  }
  for (int mf = 0; mf < 4; ++mf)
    for (int nf = 0; nf < 4; ++nf)
      for (int r = 0; r < 4; ++r) {
        size_t t = rowbase + mf * 16 + lg * 4 + r;
        out[t * NN + mq + nf * 16 + lr] = acc[mf][nf][r];
      }
}

extern "C" void kernel_launch(void* const* d_in, const int* in_sizes, int n_in,
                              void* d_out, int out_size, void* d_ws, size_t ws_size,
                              hipStream_t stream) {
  const float* x         = (const float*)d_in[0];
  const float* nu_log    = (const float*)d_in[1];
  const float* theta_log = (const float*)d_in[2];
  const float* gamma_log = (const float*)d_in[3];
  const float* B_re      = (const float*)d_in[4];
  const float* B_im      = (const float*)d_in[5];
  const float* C_re      = (const float*)d_in[6];
  const float* C_im      = (const float*)d_in[7];
  float* out = (float*)d_out;

  // d_ws usage: 2,756,608 bytes — VERBATIM R9 layout (passed).
  char* ws = (char*)d_ws;
  float2*  carrySeed = (float2*)(ws + 0);        // 1024*256*8 = 2,097,152
  float2*  Lc   = (float2*)(ws + 2097152);       // 2,048
  float2*  LCH  = (float2*)(ws + 2099200);       // 2,048
  ushort*  BnRe = (ushort*)(ws + 2101248);       // 131,072
  ushort*  BnIm = (ushort*)(ws + 2232320);       // 131,072
  ushort*  CRe  = (ushort*)(ws + 2363392);       // 131,072
  ushort*  CIm  = (ushort*)(ws + 2494464);       // 131,072  (end 2,625,536)
  float2*  Lpow = (float2*)(ws + 2625536);       // 64*256*8 = 131,072 (end 2,756,608)

  hipLaunchKernelGGL(k_setup, dim3(NN + 1), dim3(NN), 0, stream,
                     nu_log, theta_log, gamma_log, B_re, B_im, C_re, C_im,
                     Lc, LCH, Lpow, BnRe, BnIm, CRe, CIm);
  hipLaunchKernelGGL(k_carry, dim3(NCHUNK), dim3(256), 0, stream,
                     x, BnRe, BnIm, Lpow, carrySeed);
  hipLaunchKernelGGL(k_seed, dim3(NB), dim3(NN), 0, stream, carrySeed, LCH);
  hipLaunchKernelGGL(k_out, dim3(NCHUNK), dim3(256), 0, stream,
                     x, BnRe, BnIm, Lc, carrySeed, CRe, CIm, out);
}